// Round 10
// baseline (159.348 us; speedup 1.0000x reference)
//
#include <hip/hip_runtime.h>
#include <math.h>

// Problem constants (reference: N=32, K=16, BINS=100, DIM=2, sample_size=100)
#define NBINS 100
#define NN    32
#define KD    16
#define NT    99    // sample_size-1

// ws float offsets
#define OFF_H   0        // h[p][j][d] 100*16*2 = 3200
#define OFF_QT  3200     // qt[j][n] = Q[n][j]  16*32 = 512
#define OFF_XL  3712     // x_last 64
#define OFF_C   3776     // c_j = sigma^-2 * mu_j (16)
#define OFF_P   3792     // [0]=sigma_sq_inv

// ---------------- f32 cross-lane primitives (VALU-only, no DS) -------------
template<int CTRL>
__device__ __forceinline__ float fmov_dpp(float x) {
  return __int_as_float(
      __builtin_amdgcn_update_dpp(0, __float_as_int(x), CTRL, 0xf, 0xf, true));
}
__device__ __forceinline__ float frdlane(float x, int lane) {
  return __int_as_float(__builtin_amdgcn_readlane(__float_as_int(x), lane));
}
// whole-wave shift-up-by-1: out[l] = in[l-1], out[0] = c0  (row_shr:1 + fixups)
__device__ __forceinline__ float fshup(float x, float c0, int lane) {
  float v = fmov_dpp<0x111>(x);
  float x15 = frdlane(x, 15), x31 = frdlane(x, 31), x47 = frdlane(x, 47);
  v = (lane == 0)  ? c0  : v;
  v = (lane == 16) ? x15 : v;
  v = (lane == 32) ? x31 : v;
  v = (lane == 48) ? x47 : v;
  return v;
}
// element k (0..99) from (lo,hi) register pair; k wave-uniform
__device__ __forceinline__ float frdpos(float lo, float hi, int k) {
  return (k < 64) ? frdlane(lo, k) : frdlane(hi, k - 64);
}
// fast f32 reciprocal: HW rcp + 1 Newton step (~1 ulp)
__device__ __forceinline__ float frcp(float x) {
  float r = __builtin_amdgcn_rcpf(x);
  return r * (2.0f - x * r);
}
// 1-of-8 select by runtime id (7 cndmasks; all array indices compile-time)
__device__ __forceinline__ float sel8f(const float a[8], int id) {
  float s0 = (id & 1) ? a[1] : a[0];
  float s1 = (id & 1) ? a[3] : a[2];
  float s2 = (id & 1) ? a[5] : a[4];
  float s3 = (id & 1) ? a[7] : a[6];
  float t0 = (id & 2) ? s1 : s0;
  float t1 = (id & 2) ? s3 : s2;
  return (id & 4) ? t1 : t0;
}
// rotation coeffs (c, signed s) for element index e under xor-mask m.
// pair id = delete_bit_hb(e with bit hb cleared via partner map); sign:
// bit hb set (q-member) -> +s, clear (p-member) -> -s. Matches the LDS
// version's csC[p]=c,csS[p]=-s / csC[q]=c,csS[q]=+s table semantics.
__device__ __forceinline__ void paircoef(
    const float cu[8], const float su[8], int e, int m, int hb, int lowm,
    float& c_, float& s_) {
  int hib = (e >> hb) & 1;
  int pe = hib ? (e ^ m) : e;
  int id = ((pe >> (hb + 1)) << hb) | (pe & lowm);
  c_ = sel8f(cu, id);
  float sv = sel8f(su, id);
  s_ = hib ? sv : -sv;
}

// ====================== K0: eig(C^T C) + Q + params (1 wave, f32) ==========
// Fully in-register Jacobi: lane l owns row r=l>>2, cols c0+4k (A,V in 4+4
// VGPRs). Per round: (c,s) of all 8 pairs wave-uniform via 24 readlanes
// (compile-time lanes after m-unroll) -> per-lane coeff select (cndmask
// trees) -> partner values via __shfl_xor -> fma. ZERO LDS / barriers in
// the 75-round loop. xor-pair tournament masks m=1..15, 5 sweeps.
__global__ __launch_bounds__(64) void k0_eig(
    const float* __restrict__ x0, const float* __restrict__ v,
    const float* __restrict__ sigma_in, const float* __restrict__ Cq,
    float* __restrict__ ws)
{
  __shared__ float CqS[NN * KD];
  __shared__ float Vlds[16 * 17];
  const int l = threadIdx.x;
  const int r = l >> 2, c0 = l & 3;
  float sig = fmaxf(sigma_in[0], 0.05f);          // clip(sigma, 5/BINS)
  const double sinvd = 1.0 / ((double)sig * (double)sig);

  for (int e = l; e < NN * KD; e += 64) CqS[e] = Cq[e];

  {                                                // x_last
    float acc = 0.f;
    for (int p = 0; p < NBINS; ++p) acc += v[p * 64 + l];
    ws[OFF_XL + l] = x0[l] + 0.01f * acc;
  }
  __syncthreads();

  float Ar[4], Vr[4];
  #pragma unroll
  for (int k = 0; k < 4; ++k) {                    // G = Cq^T Cq ; V = I
    int ci = c0 + 4 * k;
    float acc = 0.f;
    for (int n = 0; n < NN; ++n)
      acc += CqS[n * 16 + r] * CqS[n * 16 + ci];
    Ar[k] = acc;
    Vr[k] = (r == ci) ? 1.0f : 0.0f;
  }

  for (int sweep = 0; sweep < 5; ++sweep) {
    #pragma unroll
    for (int m = 1; m <= 15; ++m) {
      const int hb = (m >= 8) ? 3 : ((m >= 4) ? 2 : ((m >= 2) ? 1 : 0));
      const int lowm = (1 << hb) - 1;
      // --- (c,s) for all 8 pairs, wave-uniform (readlane -> VALU) ---
      float cu[8], su[8];
      #pragma unroll
      for (int i = 0; i < 8; ++i) {
        const int p = ((i & ~lowm) << 1) | (i & lowm);
        const int q = p ^ m;
        float app = frdlane(Ar[p >> 2], (p << 2) | (p & 3));
        float aqq = frdlane(Ar[q >> 2], (q << 2) | (q & 3));
        float apq = frdlane(Ar[q >> 2], (p << 2) | (q & 3));
        float cc_ = 1.0f, ss_ = 0.0f;
        if (fabsf(apq) > 1e-30f) {
          float th = (aqq - app) * 0.5f * __builtin_amdgcn_rcpf(apq);
          float t_ = __builtin_amdgcn_rcpf(fabsf(th) + sqrtf(th * th + 1.0f));
          t_ = (th >= 0.0f) ? t_ : -t_;
          cc_ = __builtin_amdgcn_rsqf(t_ * t_ + 1.0f);
          ss_ = t_ * cc_;
        }
        cu[i] = cc_; su[i] = ss_;
      }
      // --- per-lane coefficients ---
      float cr, br;
      paircoef(cu, su, r, m, hb, lowm, cr, br);
      // --- rotation: partner values via shfl_xor, all-register fma ---
      const int M1 = m << 2, M2 = m & 3, M3 = M1 | M2, kx = m >> 2;
      float nA[4], nV[4];
      #pragma unroll
      for (int k = 0; k < 4; ++k) {
        float ck_, sk_;
        paircoef(cu, su, c0 + 4 * k, m, hb, lowm, ck_, sk_);
        float a_hc = __shfl_xor(Ar[k], M1, 64);
        float a_rh = (M2 == 0) ? Ar[k ^ kx] : __shfl_xor(Ar[k ^ kx], M2, 64);
        float a_hh = __shfl_xor(Ar[k ^ kx], M3, 64);
        float v_rh = (M2 == 0) ? Vr[k ^ kx] : __shfl_xor(Vr[k ^ kx], M2, 64);
        nA[k] = ck_ * (cr * Ar[k] + br * a_hc) + sk_ * (cr * a_rh + br * a_hh);
        nV[k] = ck_ * Vr[k] + sk_ * v_rh;
      }
      #pragma unroll
      for (int k = 0; k < 4; ++k) { Ar[k] = nA[k]; Vr[k] = nV[k]; }
    }
  }

  // ---- outputs ----
  #pragma unroll
  for (int k = 0; k < 4; ++k) Vlds[r * 17 + c0 + 4 * k] = Vr[k];
  if (c0 == (r & 3)) {                             // lane holding A[r][r]
    int kk = r >> 2;
    float d = (kk & 2) ? ((kk & 1) ? Ar[3] : Ar[2])
                       : ((kk & 1) ? Ar[1] : Ar[0]);
    if (d < 0.f) d = 0.f;
    ws[OFF_C + r] = (float)(sinvd * (double)d);
  }
  if (l == 0) ws[OFF_P + 0] = (float)sinvd;
  __syncthreads();
  for (int e = l; e < 512; e += 64) {              // QT[j][n] = (C*U)[n][j]
    int jq = e >> 5, n = e & 31;
    float acc = 0.f;
    for (int k2 = 0; k2 < 16; ++k2)
      acc += CqS[n * 16 + k2] * Vlds[k2 * 17 + jq];
    ws[OFF_QT + e] = acc;
  }
}

// ========== K1: per-eigenvalue Toeplitz solve via SCHUR (f32, no DS loop) ==
// 16 blocks x 1 wave. Solve (I + c_j*T) x = s_j (2 RHS), T Toeplitz.
// Generator recursion: readlane + 1-instr rcp only; forward solve by residual
// update (no inner products); L~ rows streamed to LDS; backward solve reads
// contiguous rows with prefetch. f32 (cond ~1e4; output is bf16-compared).
__global__ __launch_bounds__(64) void k1_schur(
    const float* __restrict__ v_in, const float* __restrict__ ls_in,
    float* __restrict__ ws)
{
  extern __shared__ float fsm[];
  float* Lrow  = fsm;                          // 100*101
  float* sdInv = Lrow + 100 * 101;             // 100
  float* vT    = sdInv + 100;                  // 64*101
  float* qs    = vT + 64 * 101;                // 32

  const int l = threadIdx.x;
  const int j = blockIdx.x;
  const float c = ws[OFF_C + j];
  const float sinvf = ws[OFF_P + 0];
  const float ls = ls_in[0];
  const float i2 = -0.5f / (ls * ls);
  const int ahi = 64 + l;
  const bool hiv = (ahi < 100);

  for (int p = 0; p < NBINS; ++p) vT[l * 101 + p] = v_in[p * 64 + l];
  if (l < 32) qs[l] = ws[OFF_QT + j * 32 + l];
  __syncthreads();

  // s at p = l (lo) and p = 64+l (hi)
  float s0l = 0.f, s1l = 0.f, s0h = 0.f, s1h = 0.f;
  for (int n = 0; n < NN; ++n) {
    float qv = qs[n];
    s0l += qv * vT[(2 * n) * 101 + l];
    s1l += qv * vT[(2 * n + 1) * 101 + l];
    if (hiv) {
      s0h += qv * vT[(2 * n) * 101 + ahi];
      s1h += qv * vT[(2 * n + 1) * 101 + ahi];
    }
  }

  // normalized Toeplitz first column t_k = c*g_k/m0 ; b = s/m0
  const float m0  = 1.0f + c * (1.0f + 1e-5f);
  const float im0 = frcp(m0);
  float gl = expf((0.01f * (float)l) * (0.01f * (float)l) * i2);
  float gh = expf((0.01f * (float)ahi) * (0.01f * (float)ahi) * i2);
  float u_lo = (l == 0) ? 1.0f : c * gl * im0;
  float u_hi = hiv ? c * gh * im0 : 0.0f;
  float v_lo = (l == 0) ? 0.0f : u_lo;          // v = (0, t1, ..)
  float v_hi = u_hi;
  float r0_lo = s0l * im0, r1_lo = s1l * im0;
  float r0_hi = hiv ? s0h * im0 : 0.0f;
  float r1_hi = hiv ? s1h * im0 : 0.0f;
  float P = 1.0f;

  // ---- forward: Schur recursion + residual solve + L~ row streaming ----
  for (int k = 0; k < 100; ++k) {
    float uk  = frdpos(u_lo, u_hi, k);
    float iuk = frcp(uk);
    float r0k = frdpos(r0_lo, r0_hi, k);
    float r1k = frdpos(r1_lo, r1_hi, k);
    Lrow[l * 101 + k] = u_lo * iuk;             // L~[:,k] stored by rows
    if (hiv) Lrow[ahi * 101 + k] = u_hi * iuk;
    if (l == 0) sdInv[k] = P * iuk * iuk;       // 1/d_k
    float a0 = r0k * iuk, a1 = r1k * iuk;
    if (l > k)   { r0_lo -= a0 * u_lo; r1_lo -= a1 * u_lo; }
    if (ahi > k) { r0_hi -= a0 * u_hi; r1_hi -= a1 * u_hi; }
    if (k < 99) {
      float vk1 = frdpos(v_lo, v_hi, k + 1);
      float g = vk1 * iuk;
      float u63 = frdlane(u_lo, 63);
      float u1_lo = fshup(u_lo, 0.0f, l);       // Z u
      float u1_hi = fshup(u_hi, u63, l);
      u_lo = u1_lo - g * v_lo;  u_hi = u1_hi - g * v_hi;
      v_lo = v_lo - g * u1_lo;  v_hi = v_hi - g * u1_hi;
      P *= (1.0f - g * g);
    }
  }
  __syncthreads();                               // Lrow/sdInv visible

  // ---- diagonal scale: w = y / d ----
  float sd_l = sdInv[l];
  float sd_h = hiv ? sdInv[ahi] : 0.0f;
  float x0_lo = r0_lo * sd_l, x1_lo = r1_lo * sd_l;
  float x0_hi = r0_hi * sd_h, x1_hi = r1_hi * sd_h;

  // ---- backward: L~^T x = w, residual update with row reads (prefetched) --
  float Ll = Lrow[99 * 101 + l];
  float Lh = hiv ? Lrow[99 * 101 + ahi] : 0.0f;
  for (int k = 99; k >= 1; --k) {
    float nLl = Lrow[(k - 1) * 101 + l];
    float nLh = hiv ? Lrow[(k - 1) * 101 + ahi] : 0.0f;
    float xk0 = frdpos(x0_lo, x0_hi, k);
    float xk1 = frdpos(x1_lo, x1_hi, k);
    if (l < k)   { x0_lo -= xk0 * Ll; x1_lo -= xk1 * Ll; }
    if (ahi < k) { x0_hi -= xk0 * Lh; x1_hi -= xk1 * Lh; }
    Ll = nLl; Lh = nLh;
  }

  // h[p][j][d] = sinv * x[p]
  ws[OFF_H + l * 32 + j * 2 + 0] = sinvf * x0_lo;
  ws[OFF_H + l * 32 + j * 2 + 1] = sinvf * x1_lo;
  if (hiv) {
    ws[OFF_H + ahi * 32 + j * 2 + 0] = sinvf * x0_hi;
    ws[OFF_H + ahi * 32 + j * 2 + 1] = sinvf * x1_hi;
  }
}

// =============================== K_TAIL ====================================
// 16 blocks x 256: stage h/Q^T/xl, Bc table, z = Bc*h, xt, intensity pairs.
#define L_H   0        // 3200
#define L_QT  3200     // 512
#define L_XL  3712     // 64
#define L_BC  3776     // 99*100 = 9900
#define L_Z   13676    // 99*32  = 3168
#define L_XT  16844    // 99*64  = 6336
#define L_PS  23180    // 4*64   = 256
#define L_TOT 23436

__global__ __launch_bounds__(256) void k_tail(
    const float* __restrict__ ls_in, const float* __restrict__ beta,
    const float* __restrict__ ws, float* __restrict__ out)
{
  extern __shared__ float lds[];
  const int tid = threadIdx.x;
  const float ls = ls_in[0];
  const float i2 = -0.5f / (ls * ls);

  for (int e = tid; e < 3200; e += 256) lds[L_H + e] = ws[OFF_H + e];
  for (int e = tid; e < 512; e += 256)  lds[L_QT + e] = ws[OFF_QT + e];
  if (tid < 64) lds[L_XL + tid] = ws[OFF_XL + tid];
  for (int e = tid; e < NT * NBINS; e += 256) {
    int t = e / NBINS, p = e - t * NBINS;
    float tst = 1.0f + (float)t * (1.0f / 99.0f);
    float dd = tst - ((float)p + 0.5f) * 0.01f;
    lds[L_BC + e] = expf(dd * dd * i2);
  }
  __syncthreads();

  // z[t][j][d] = sum_p Bc[t][p] * h[p][j][d]
  for (int dot = tid; dot < NT * 32; dot += 256) {
    int t = dot >> 5, jd = dot & 31;
    float acc = 0.f;
    for (int p = 0; p < NBINS; ++p)
      acc += lds[L_BC + t * NBINS + p] * lds[L_H + p * 32 + jd];
    lds[L_Z + dot] = acc;
  }
  __syncthreads();

  // xt[t][n][d] = xl[nd] + trel * sum_j qt[j][n] * z[t][j][d]
  for (int e = tid; e < NT * 64; e += 256) {
    int t = e >> 6, nd = e & 63, n = nd >> 1, d = nd & 1;
    float acc = 0.f;
    for (int jq = 0; jq < 16; ++jq)
      acc += lds[L_QT + jq * 32 + n] * lds[L_Z + t * 32 + jq * 2 + d];
    float trel = (float)t * (1.0f / 99.0f);
    lds[L_XT + e] = lds[L_XL + nd] + trel * acc;
  }
  __syncthreads();

  // intensity: 64 pairs per block, 4-way t-split
  {
    const int pl = tid & 63, tc = tid >> 6;
    const int gp = blockIdx.x * 64 + pl;
    const int i = gp >> 5, jj = gp & 31;
    const float bsum = beta[i] + beta[jj];
    const int t0 = tc * 25, t1 = (t0 + 25 < NT) ? t0 + 25 : NT;
    float acc = 0.f;
    for (int t = t0; t < t1; ++t) {
      float2 xi = *(const float2*)&lds[L_XT + t * 64 + 2 * i];
      float2 xj = *(const float2*)&lds[L_XT + t * 64 + 2 * jj];
      float dx = xi.x - xj.x, dy = xi.y - xj.y;
      float sq = fmaxf(dx * dx + dy * dy, 1e-12f);
      acc += expf(bsum - sqrtf(sq));
    }
    lds[L_PS + tc * 64 + pl] = acc;
  }
  __syncthreads();
  if (tid < 64) {
    float s = lds[L_PS + tid] + lds[L_PS + 64 + tid]
            + lds[L_PS + 128 + tid] + lds[L_PS + 192 + tid];
    out[blockIdx.x * 64 + tid] = s * (1.0f / 99.0f);
  }
}

extern "C" void kernel_launch(void* const* d_in, const int* in_sizes, int n_in,
                              void* d_out, int out_size, void* d_ws, size_t ws_size,
                              hipStream_t stream) {
  const float* x0    = (const float*)d_in[0];
  const float* v     = (const float*)d_in[1];
  const float* beta  = (const float*)d_in[2];
  const float* sigma = (const float*)d_in[3];
  // d_in[4] = x0c: unused (B_cross row 0 is zero)
  const float* ls    = (const float*)d_in[5];
  const float* Cq    = (const float*)d_in[6];
  float* out = (float*)d_out;
  float* ws  = (float*)d_ws;

  k0_eig<<<1, 64, 0, stream>>>(x0, v, sigma, Cq, ws);
  const size_t smem1 = (size_t)(100 * 101 + 100 + 64 * 101 + 32) * sizeof(float); // ~67 KB
  k1_schur<<<16, 64, smem1, stream>>>(v, ls, ws);
  k_tail<<<16, 256, (size_t)L_TOT * sizeof(float), stream>>>(ls, beta, ws, out);
}

// Round 11
// 116.154 us; speedup vs baseline: 1.3719x; 1.3719x over previous
//
#include <hip/hip_runtime.h>
#include <math.h>

// Problem constants (reference: N=32, K=16, BINS=100, DIM=2, sample_size=100)
#define NBINS 100
#define NN    32
#define KD    16
#define NT    99    // sample_size-1

// ws float offsets
#define OFF_H   0        // h[p][j][d] 100*16*2 = 3200
#define OFF_QT  3200     // qt[j][n] = Q[n][j]  16*32 = 512
#define OFF_XL  3712     // x_last 64

// ---------------- f32 cross-lane primitives (VALU-only) --------------------
template<int CTRL>
__device__ __forceinline__ float fmov_dpp(float x) {
  return __int_as_float(
      __builtin_amdgcn_update_dpp(0, __float_as_int(x), CTRL, 0xf, 0xf, true));
}
__device__ __forceinline__ float frdlane(float x, int lane) {
  return __int_as_float(__builtin_amdgcn_readlane(__float_as_int(x), lane));
}
// whole-wave shift-up-by-1: out[l] = in[l-1], out[0] = c0  (row_shr:1 + fixups)
__device__ __forceinline__ float fshup(float x, float c0, int lane) {
  float v = fmov_dpp<0x111>(x);
  float x15 = frdlane(x, 15), x31 = frdlane(x, 31), x47 = frdlane(x, 47);
  v = (lane == 0)  ? c0  : v;
  v = (lane == 16) ? x15 : v;
  v = (lane == 32) ? x31 : v;
  v = (lane == 48) ? x47 : v;
  return v;
}
// element k (0..99) from (lo,hi) register pair; k wave-uniform
__device__ __forceinline__ float frdpos(float lo, float hi, int k) {
  return (k < 64) ? frdlane(lo, k) : frdlane(hi, k - 64);
}
// fast f32 reciprocal: HW rcp + 1 Newton step (~1 ulp)
__device__ __forceinline__ float frcp(float x) {
  float r = __builtin_amdgcn_rcpf(x);
  return r * (2.0f - x * r);
}

// ================= K1: eig (redundant per block) + Toeplitz solve ==========
// 16 blocks x 1 wave. Each block: stage vT+Cq; f32 LDS Jacobi (proven
// round-8 structure, 4 sweeps); c_j and Q locally; s-projection; Schur
// forward with SCALAR LOOKAHEAD (critical chain = rcp->mul->fma only,
// all readlanes hit pre-update vectors); diag; backward. Block 0 also
// publishes QT and x_last for the tail kernel.
__global__ __launch_bounds__(64) void k1_all(
    const float* __restrict__ x0, const float* __restrict__ v_in,
    const float* __restrict__ sigma_in, const float* __restrict__ ls_in,
    const float* __restrict__ Cq, float* __restrict__ ws)
{
  extern __shared__ float fsm[];
  float* Lrow  = fsm;                          // 100*101 = 10100
  float* sdInv = Lrow + 100 * 101;             // 100
  float* vT    = sdInv + 100;                  // 64*101 = 6464
  float* QTl   = vT + 64 * 101;                // 512
  __shared__ float A[16 * 17], Vv[16 * 17];
  __shared__ float csC[16], csS[16];
  __shared__ float CqS[NN * KD];

  const int l = threadIdx.x;
  const int j = blockIdx.x;
  const int r = l >> 2, c0 = l & 3;
  const float ls = ls_in[0];
  const float i2 = -0.5f / (ls * ls);
  float sig = fmaxf(sigma_in[0], 0.05f);       // clip(sigma, 5/BINS)
  const double sinvd = 1.0 / ((double)sig * (double)sig);
  const float sinvf = (float)sinvd;
  const int ahi = 64 + l;
  const bool hiv = (ahi < 100);

  // ---- stage: vT (transposed), CqS ----
  for (int p = 0; p < NBINS; ++p) vT[l * 101 + p] = v_in[p * 64 + l];
  for (int e = l; e < NN * KD; e += 64) CqS[e] = Cq[e];
  __syncthreads();

  if (j == 0) {                                // x_last (block 0 only)
    float acc = 0.f;
    for (int p = 0; p < NBINS; ++p) acc += vT[l * 101 + p];
    ws[OFF_XL + l] = x0[l] + 0.01f * acc;
  }

  // ---- G = Cq^T Cq ; V = I ----
  #pragma unroll
  for (int k = 0; k < 4; ++k) {
    int ci = c0 + 4 * k;
    float acc = 0.f;
    for (int n = 0; n < NN; ++n)
      acc += CqS[n * 16 + r] * CqS[n * 16 + ci];
    A[r * 17 + ci] = acc;
    Vv[r * 17 + ci] = (r == ci) ? 1.0f : 0.0f;
  }
  __syncthreads();

  // ---- Jacobi (fused one-phase, f32, 4 sweeps x 15 xor-masks) ----
  for (int sweep = 0; sweep < 4; ++sweep)
  for (int m = 1; m <= 15; ++m) {
    const int hb = 31 - __clz(m);
    const int lowm = (1 << hb) - 1;
    if (l < 8) {                               // (c,s) per pair
      int p = ((l & ~lowm) << 1) | (l & lowm), q = p ^ m;
      float app = A[p * 17 + p], aqq = A[q * 17 + q], apq = A[p * 17 + q];
      float c = 1.0f, s = 0.0f;
      if (fabsf(apq) > 1e-30f) {
        float th = (aqq - app) * 0.5f * __builtin_amdgcn_rcpf(apq);
        float t_ = __builtin_amdgcn_rcpf(fabsf(th) + sqrtf(th * th + 1.0f));
        t_ = (th >= 0.0f) ? t_ : -t_;
        c = __builtin_amdgcn_rsqf(t_ * t_ + 1.0f);
        s = t_ * c;
      }
      csC[p] = c; csS[p] = -s;
      csC[q] = c; csS[q] = s;
    }
    __syncthreads();
    const int rh = r ^ m;
    float ar = csC[r], br = csS[r];
    float nA[4], nV[4];
    #pragma unroll
    for (int k = 0; k < 4; ++k) {
      int ci = c0 + 4 * k, ch = ci ^ m;
      float ac = csC[ci], bc = csS[ci];
      float a_rc = A[r * 17 + ci],  a_hc = A[rh * 17 + ci];
      float a_rh = A[r * 17 + ch],  a_hh = A[rh * 17 + ch];
      float v_rc = Vv[r * 17 + ci], v_rh = Vv[r * 17 + ch];
      nA[k] = ac * (ar * a_rc + br * a_hc) + bc * (ar * a_rh + br * a_hh);
      nV[k] = ac * v_rc + bc * v_rh;
    }
    __syncthreads();                           // all reads done
    #pragma unroll
    for (int k = 0; k < 4; ++k) {
      int ci = c0 + 4 * k;
      A[r * 17 + ci] = nA[k];
      Vv[r * 17 + ci] = nV[k];
    }
    __syncthreads();
  }

  // ---- c_j (broadcast), Q^T local (+publish by block 0) ----
  float muj = A[j * 17 + j];
  if (muj < 0.f) muj = 0.f;
  const float c = (float)(sinvd * (double)muj);
  for (int e = l; e < 512; e += 64) {          // QT[jq][n] = (C*U)[n][jq]
    int jq = e >> 5, n = e & 31;
    float acc = 0.f;
    for (int k2 = 0; k2 < 16; ++k2)
      acc += CqS[n * 16 + k2] * Vv[k2 * 17 + jq];
    QTl[e] = acc;
    if (j == 0) ws[OFF_QT + e] = acc;
  }
  __syncthreads();

  // ---- s-projection: s[d][p] at p=l (lo) / p=64+l (hi) ----
  float s0l = 0.f, s1l = 0.f, s0h = 0.f, s1h = 0.f;
  for (int n = 0; n < NN; ++n) {
    float qv = QTl[j * 32 + n];                // broadcast
    s0l += qv * vT[(2 * n) * 101 + l];
    s1l += qv * vT[(2 * n + 1) * 101 + l];
    if (hiv) {
      s0h += qv * vT[(2 * n) * 101 + ahi];
      s1h += qv * vT[(2 * n + 1) * 101 + ahi];
    }
  }

  // ---- normalized Toeplitz: t_k = c*g_k/m0 ; b = s/m0 ----
  const float m0  = 1.0f + c * (1.0f + 1e-5f);
  const float im0 = frcp(m0);
  float gl = expf((0.01f * (float)l) * (0.01f * (float)l) * i2);
  float gh = expf((0.01f * (float)ahi) * (0.01f * (float)ahi) * i2);
  float u_lo = (l == 0) ? 1.0f : c * gl * im0;
  float u_hi = hiv ? c * gh * im0 : 0.0f;
  float v_lo = (l == 0) ? 0.0f : u_lo;          // v = (0, t1, ..)
  float v_hi = u_hi;
  float r0_lo = s0l * im0, r1_lo = s1l * im0;
  float r0_hi = hiv ? s0h * im0 : 0.0f;
  float r1_hi = hiv ? s1h * im0 : 0.0f;
  float P = 1.0f;

  // ---- forward Schur with scalar lookahead ----
  // scalars: uk=u[k], uk1=u[k+1], vk1=v[k+1], vk2=v[k+2], r0k=r0[k], r1k=r1[k]
  float uk  = frdlane(u_lo, 0);
  float uk1 = frdlane(u_lo, 1);
  float vk1 = frdlane(v_lo, 1);
  float vk2 = frdlane(v_lo, 2);
  float r0k = frdlane(r0_lo, 0);
  float r1k = frdlane(r1_lo, 0);

  for (int k = 0; k < 100; ++k) {
    float iuk = frcp(uk);
    // off-chain: L column store + diag
    Lrow[l * 101 + k] = u_lo * iuk;
    if (hiv) Lrow[ahi * 101 + k] = u_hi * iuk;
    if (l == 0) sdInv[k] = P * iuk * iuk;
    float a0 = r0k * iuk, a1 = r1k * iuk;
    // parallel readlanes of PRE-UPDATE vectors
    int k1i = (k + 1 < 100) ? k + 1 : 99;
    int k2i = (k + 2 < 100) ? k + 2 : 99;
    int k3i = (k + 3 < 100) ? k + 3 : 99;
    float r0k1 = frdpos(r0_lo, r0_hi, k1i);
    float r1k1 = frdpos(r1_lo, r1_hi, k1i);
    float uk2  = frdpos(u_lo, u_hi, k2i);
    float vk3  = frdpos(v_lo, v_hi, k3i);
    // residual vector update (uses current u)
    if (l > k)   { r0_lo -= a0 * u_lo; r1_lo -= a1 * u_lo; }
    if (ahi > k) { r0_hi -= a0 * u_hi; r1_hi -= a1 * u_hi; }
    // residual scalar lookahead
    r0k = r0k1 - a0 * uk1;
    r1k = r1k1 - a1 * uk1;
    if (k < 99) {
      float g = vk1 * iuk;
      float u63 = frdlane(u_lo, 63);
      float u1_lo = fshup(u_lo, 0.0f, l);       // Z u
      float u1_hi = fshup(u_hi, u63, l);
      float nu_lo = u1_lo - g * v_lo, nu_hi = u1_hi - g * v_hi;
      v_lo = v_lo - g * u1_lo;  v_hi = v_hi - g * u1_hi;
      u_lo = nu_lo;             u_hi = nu_hi;
      P *= (1.0f - g * g);
      // generator scalar lookahead
      float uk_n  = uk  - g * vk1;
      float uk1_n = uk1 - g * vk2;
      float vk1_n = vk2 - g * uk1;
      float vk2_n = vk3 - g * uk2;
      uk = uk_n; uk1 = uk1_n; vk1 = vk1_n; vk2 = vk2_n;
    }
  }
  __syncthreads();                              // Lrow/sdInv visible

  // ---- diagonal scale: w = y / d ----
  float sd_l = sdInv[l];
  float sd_h = hiv ? sdInv[ahi] : 0.0f;
  float x0_lo = r0_lo * sd_l, x1_lo = r1_lo * sd_l;
  float x0_hi = r0_hi * sd_h, x1_hi = r1_hi * sd_h;

  // ---- backward: L~^T x = w, residual update with prefetched row reads ----
  float Ll = Lrow[99 * 101 + l];
  float Lh = hiv ? Lrow[99 * 101 + ahi] : 0.0f;
  for (int k = 99; k >= 1; --k) {
    float nLl = Lrow[(k - 1) * 101 + l];
    float nLh = hiv ? Lrow[(k - 1) * 101 + ahi] : 0.0f;
    float xk0 = frdpos(x0_lo, x0_hi, k);
    float xk1 = frdpos(x1_lo, x1_hi, k);
    if (l < k)   { x0_lo -= xk0 * Ll; x1_lo -= xk1 * Ll; }
    if (ahi < k) { x0_hi -= xk0 * Lh; x1_hi -= xk1 * Lh; }
    Ll = nLl; Lh = nLh;
  }

  // ---- h[p][j][d] = sinv * x[p] ----
  ws[OFF_H + l * 32 + j * 2 + 0] = sinvf * x0_lo;
  ws[OFF_H + l * 32 + j * 2 + 1] = sinvf * x1_lo;
  if (hiv) {
    ws[OFF_H + ahi * 32 + j * 2 + 0] = sinvf * x0_hi;
    ws[OFF_H + ahi * 32 + j * 2 + 1] = sinvf * x1_hi;
  }
}

// =============================== K_TAIL ====================================
// 16 blocks x 256: stage h/Q^T/xl, Bc table, z = Bc*h, xt, intensity pairs.
#define L_H   0        // 3200
#define L_QT  3200     // 512
#define L_XL  3712     // 64
#define L_BC  3776     // 99*100 = 9900
#define L_Z   13676    // 99*32  = 3168
#define L_XT  16844    // 99*64  = 6336
#define L_PS  23180    // 4*64   = 256
#define L_TOT 23436

__global__ __launch_bounds__(256) void k_tail(
    const float* __restrict__ ls_in, const float* __restrict__ beta,
    const float* __restrict__ ws, float* __restrict__ out)
{
  extern __shared__ float lds[];
  const int tid = threadIdx.x;
  const float ls = ls_in[0];
  const float i2 = -0.5f / (ls * ls);

  for (int e = tid; e < 3200; e += 256) lds[L_H + e] = ws[OFF_H + e];
  for (int e = tid; e < 512; e += 256)  lds[L_QT + e] = ws[OFF_QT + e];
  if (tid < 64) lds[L_XL + tid] = ws[OFF_XL + tid];
  for (int e = tid; e < NT * NBINS; e += 256) {
    int t = e / NBINS, p = e - t * NBINS;
    float tst = 1.0f + (float)t * (1.0f / 99.0f);
    float dd = tst - ((float)p + 0.5f) * 0.01f;
    lds[L_BC + e] = expf(dd * dd * i2);
  }
  __syncthreads();

  // z[t][j][d] = sum_p Bc[t][p] * h[p][j][d]
  for (int dot = tid; dot < NT * 32; dot += 256) {
    int t = dot >> 5, jd = dot & 31;
    float acc = 0.f;
    for (int p = 0; p < NBINS; ++p)
      acc += lds[L_BC + t * NBINS + p] * lds[L_H + p * 32 + jd];
    lds[L_Z + dot] = acc;
  }
  __syncthreads();

  // xt[t][n][d] = xl[nd] + trel * sum_j qt[j][n] * z[t][j][d]
  for (int e = tid; e < NT * 64; e += 256) {
    int t = e >> 6, nd = e & 63, n = nd >> 1, d = nd & 1;
    float acc = 0.f;
    for (int jq = 0; jq < 16; ++jq)
      acc += lds[L_QT + jq * 32 + n] * lds[L_Z + t * 32 + jq * 2 + d];
    float trel = (float)t * (1.0f / 99.0f);
    lds[L_XT + e] = lds[L_XL + nd] + trel * acc;
  }
  __syncthreads();

  // intensity: 64 pairs per block, 4-way t-split
  {
    const int pl = tid & 63, tc = tid >> 6;
    const int gp = blockIdx.x * 64 + pl;
    const int i = gp >> 5, jj = gp & 31;
    const float bsum = beta[i] + beta[jj];
    const int t0 = tc * 25, t1 = (t0 + 25 < NT) ? t0 + 25 : NT;
    float acc = 0.f;
    for (int t = t0; t < t1; ++t) {
      float2 xi = *(const float2*)&lds[L_XT + t * 64 + 2 * i];
      float2 xj = *(const float2*)&lds[L_XT + t * 64 + 2 * jj];
      float dx = xi.x - xj.x, dy = xi.y - xj.y;
      float sq = fmaxf(dx * dx + dy * dy, 1e-12f);
      acc += expf(bsum - sqrtf(sq));
    }
    lds[L_PS + tc * 64 + pl] = acc;
  }
  __syncthreads();
  if (tid < 64) {
    float s = lds[L_PS + tid] + lds[L_PS + 64 + tid]
            + lds[L_PS + 128 + tid] + lds[L_PS + 192 + tid];
    out[blockIdx.x * 64 + tid] = s * (1.0f / 99.0f);
  }
}

extern "C" void kernel_launch(void* const* d_in, const int* in_sizes, int n_in,
                              void* d_out, int out_size, void* d_ws, size_t ws_size,
                              hipStream_t stream) {
  const float* x0    = (const float*)d_in[0];
  const float* v     = (const float*)d_in[1];
  const float* beta  = (const float*)d_in[2];
  const float* sigma = (const float*)d_in[3];
  // d_in[4] = x0c: unused (B_cross row 0 is zero)
  const float* ls    = (const float*)d_in[5];
  const float* Cq    = (const float*)d_in[6];
  float* out = (float*)d_out;
  float* ws  = (float*)d_ws;

  const size_t smem1 = (size_t)(100 * 101 + 100 + 64 * 101 + 512) * sizeof(float); // ~68.7 KB
  k1_all<<<16, 64, smem1, stream>>>(x0, v, sigma, ls, Cq, ws);
  k_tail<<<16, 256, (size_t)L_TOT * sizeof(float), stream>>>(ls, beta, ws, out);
}

// Round 12
// 102.313 us; speedup vs baseline: 1.5575x; 1.1353x over previous
//
#include <hip/hip_runtime.h>
#include <math.h>

// Problem constants (reference: N=32, K=16, BINS=100, DIM=2, sample_size=100)
#define NBINS 100
#define NN    32
#define KD    16
#define NT    99    // sample_size-1

// ws float offsets
#define OFF_H   0        // h[p][j][d] 100*16*2 = 3200
#define OFF_QT  3200     // qt[j][n] = Q[n][j]  16*32 = 512
#define OFF_XL  3712     // x_last 64

// ---------------- f32 cross-lane primitives (VALU-only) --------------------
template<int CTRL>
__device__ __forceinline__ float fmov_dpp(float x) {
  return __int_as_float(
      __builtin_amdgcn_update_dpp(0, __float_as_int(x), CTRL, 0xf, 0xf, true));
}
__device__ __forceinline__ float frdlane(float x, int lane) {
  return __int_as_float(__builtin_amdgcn_readlane(__float_as_int(x), lane));
}
// whole-wave shift-up-by-1: out[l] = in[l-1], out[0] = c0  (row_shr:1 + fixups)
__device__ __forceinline__ float fshup(float x, float c0, int lane) {
  float v = fmov_dpp<0x111>(x);
  float x15 = frdlane(x, 15), x31 = frdlane(x, 31), x47 = frdlane(x, 47);
  v = (lane == 0)  ? c0  : v;
  v = (lane == 16) ? x15 : v;
  v = (lane == 32) ? x31 : v;
  v = (lane == 48) ? x47 : v;
  return v;
}
// element k (0..99) from (lo,hi) register pair; k wave-uniform
__device__ __forceinline__ float frdpos(float lo, float hi, int k) {
  return (k < 64) ? frdlane(lo, k) : frdlane(hi, k - 64);
}
// fast f32 reciprocal: HW rcp + 1 Newton step (~1 ulp)
__device__ __forceinline__ float frcp(float x) {
  float r = __builtin_amdgcn_rcpf(x);
  return r * (2.0f - x * r);
}

// readlane flavors for the forward-Schur loop split
#define RD_LO(lo, hi, idx)  frdlane(lo, idx)
#define RD_MIX(lo, hi, idx) frdpos(lo, hi, ((idx) <= 99 ? (idx) : 99))

// one forward-Schur step (scalar-lookahead form, verified round 11)
#define FWD_STEP(RD)                                                     \
  {                                                                      \
    float iuk = frcp(uk);                                                \
    Lrow[l * 101 + k] = u_lo * iuk;                                      \
    if (hiv) Lrow[ahi * 101 + k] = u_hi * iuk;                           \
    float dk = P * iuk * iuk;                                            \
    sdl = (l == k)   ? dk : sdl;                                         \
    sdh = (ahi == k) ? dk : sdh;                                         \
    float a0 = r0k * iuk, a1 = r1k * iuk;                                \
    float r0k1 = RD(r0_lo, r0_hi, k + 1);                                \
    float r1k1 = RD(r1_lo, r1_hi, k + 1);                                \
    float uk2  = RD(u_lo, u_hi, k + 2);                                  \
    float vk3  = RD(v_lo, v_hi, k + 3);                                  \
    if (l > k)   { r0_lo -= a0 * u_lo; r1_lo -= a1 * u_lo; }             \
    if (ahi > k) { r0_hi -= a0 * u_hi; r1_hi -= a1 * u_hi; }             \
    r0k = r0k1 - a0 * uk1;                                               \
    r1k = r1k1 - a1 * uk1;                                               \
    float g = vk1 * iuk;                                                 \
    float u63 = frdlane(u_lo, 63);                                       \
    float u1_lo = fshup(u_lo, 0.0f, l);                                  \
    float u1_hi = fshup(u_hi, u63, l);                                   \
    u_lo = u1_lo - g * v_lo;  u_hi = u1_hi - g * v_hi;                   \
    v_lo = v_lo - g * u1_lo;  v_hi = v_hi - g * u1_hi;                   \
    P *= (1.0f - g * g);                                                 \
    float uk_n  = uk  - g * vk1;                                         \
    float uk1_n = uk1 - g * vk2;                                         \
    float vk1_n = vk2 - g * uk1;                                         \
    float vk2_n = vk3 - g * uk2;                                         \
    uk = uk_n; uk1 = uk1_n; vk1 = vk1_n; vk2 = vk2_n;                    \
  }

// ================= K1: eig (redundant per block) + Toeplitz solve ==========
// 16 blocks x 1 wave. SINGLE-WAVE BLOCK => zero __syncthreads: lockstep
// guarantees reads-before-writes within a round; compiler lgkmcnt waits
// order write->read across phases on the same LDS arrays.
__global__ __launch_bounds__(64) void k1_all(
    const float* __restrict__ x0, const float* __restrict__ v_in,
    const float* __restrict__ sigma_in, const float* __restrict__ ls_in,
    const float* __restrict__ Cq, float* __restrict__ ws)
{
  extern __shared__ float fsm[];
  float* Lrow  = fsm;                          // 100*101 = 10100
  float* vT    = Lrow + 100 * 101;             // 64*101 = 6464
  float* QTl   = vT + 64 * 101;                // 512
  __shared__ float A[16 * 17], Vv[16 * 17];
  __shared__ float csC[16], csS[16];
  __shared__ float CqS[NN * KD];

  const int l = threadIdx.x;
  const int j = blockIdx.x;
  const int r = l >> 2, c0 = l & 3;
  const float ls = ls_in[0];
  const float i2 = -0.5f / (ls * ls);
  float sig = fmaxf(sigma_in[0], 0.05f);       // clip(sigma, 5/BINS)
  const double sinvd = 1.0 / ((double)sig * (double)sig);
  const float sinvf = (float)sinvd;
  const int ahi = 64 + l;
  const bool hiv = (ahi < 100);

  // ---- stage: vT (transposed), CqS ----
  for (int p = 0; p < NBINS; ++p) vT[l * 101 + p] = v_in[p * 64 + l];
  for (int e = l; e < NN * KD; e += 64) CqS[e] = Cq[e];

  if (j == 0) {                                // x_last (block 0 only)
    float acc = 0.f;
    for (int p = 0; p < NBINS; ++p) acc += vT[l * 101 + p];
    ws[OFF_XL + l] = x0[l] + 0.01f * acc;
  }

  // ---- G = Cq^T Cq ; V = I ----
  #pragma unroll
  for (int k = 0; k < 4; ++k) {
    int ci = c0 + 4 * k;
    float acc = 0.f;
    for (int n = 0; n < NN; ++n)
      acc += CqS[n * 16 + r] * CqS[n * 16 + ci];
    A[r * 17 + ci] = acc;
    Vv[r * 17 + ci] = (r == ci) ? 1.0f : 0.0f;
  }

  // ---- Jacobi (fused one-phase, f32, 4 sweeps x 15 xor-masks, NO barriers) --
  for (int sweep = 0; sweep < 4; ++sweep)
  for (int m = 1; m <= 15; ++m) {
    const int hb = 31 - __clz(m);
    const int lowm = (1 << hb) - 1;
    if (l < 8) {                               // (c,s) per pair
      int p = ((l & ~lowm) << 1) | (l & lowm), q = p ^ m;
      float app = A[p * 17 + p], aqq = A[q * 17 + q], apq = A[p * 17 + q];
      float c = 1.0f, s = 0.0f;
      if (fabsf(apq) > 1e-30f) {
        float th = (aqq - app) * 0.5f * __builtin_amdgcn_rcpf(apq);
        float t_ = __builtin_amdgcn_rcpf(fabsf(th) + sqrtf(th * th + 1.0f));
        t_ = (th >= 0.0f) ? t_ : -t_;
        c = __builtin_amdgcn_rsqf(t_ * t_ + 1.0f);
        s = t_ * c;
      }
      csC[p] = c; csS[p] = -s;
      csC[q] = c; csS[q] = s;
    }
    const int rh = r ^ m;
    float ar = csC[r], br = csS[r];            // ordered after writes (waitcnt)
    float nA[4], nV[4];
    #pragma unroll
    for (int k = 0; k < 4; ++k) {              // batched reads (before writes)
      int ci = c0 + 4 * k, ch = ci ^ m;
      float ac = csC[ci], bc = csS[ci];
      float a_rc = A[r * 17 + ci],  a_hc = A[rh * 17 + ci];
      float a_rh = A[r * 17 + ch],  a_hh = A[rh * 17 + ch];
      float v_rc = Vv[r * 17 + ci], v_rh = Vv[r * 17 + ch];
      nA[k] = ac * (ar * a_rc + br * a_hc) + bc * (ar * a_rh + br * a_hh);
      nV[k] = ac * v_rc + bc * v_rh;
    }
    #pragma unroll
    for (int k = 0; k < 4; ++k) {              // writes (lockstep: after reads)
      int ci = c0 + 4 * k;
      A[r * 17 + ci] = nA[k];
      Vv[r * 17 + ci] = nV[k];
    }
  }

  // ---- c_j (broadcast), Q^T local (+publish by block 0) ----
  float muj = A[j * 17 + j];
  if (muj < 0.f) muj = 0.f;
  const float c = (float)(sinvd * (double)muj);
  for (int e = l; e < 512; e += 64) {          // QT[jq][n] = (C*U)[n][jq]
    int jq = e >> 5, n = e & 31;
    float acc = 0.f;
    for (int k2 = 0; k2 < 16; ++k2)
      acc += CqS[n * 16 + k2] * Vv[k2 * 17 + jq];
    QTl[e] = acc;
    if (j == 0) ws[OFF_QT + e] = acc;
  }

  // ---- s-projection: s[d][p] at p=l (lo) / p=64+l (hi) ----
  float s0l = 0.f, s1l = 0.f, s0h = 0.f, s1h = 0.f;
  for (int n = 0; n < NN; ++n) {
    float qv = QTl[j * 32 + n];                // broadcast
    s0l += qv * vT[(2 * n) * 101 + l];
    s1l += qv * vT[(2 * n + 1) * 101 + l];
    if (hiv) {
      s0h += qv * vT[(2 * n) * 101 + ahi];
      s1h += qv * vT[(2 * n + 1) * 101 + ahi];
    }
  }

  // ---- normalized Toeplitz: t_k = c*g_k/m0 ; b = s/m0 ----
  const float m0  = 1.0f + c * (1.0f + 1e-5f);
  const float im0 = frcp(m0);
  float gl = expf((0.01f * (float)l) * (0.01f * (float)l) * i2);
  float gh = expf((0.01f * (float)ahi) * (0.01f * (float)ahi) * i2);
  float u_lo = (l == 0) ? 1.0f : c * gl * im0;
  float u_hi = hiv ? c * gh * im0 : 0.0f;
  float v_lo = (l == 0) ? 0.0f : u_lo;          // v = (0, t1, ..)
  float v_hi = u_hi;
  float r0_lo = s0l * im0, r1_lo = s1l * im0;
  float r0_hi = hiv ? s0h * im0 : 0.0f;
  float r1_hi = hiv ? s1h * im0 : 0.0f;
  float P = 1.0f;
  float sdl = 0.f, sdh = 0.f;                   // register 1/d capture

  // ---- forward Schur: scalar lookahead, split loops ----
  float uk  = frdlane(u_lo, 0);
  float uk1 = frdlane(u_lo, 1);
  float vk1 = frdlane(v_lo, 1);
  float vk2 = frdlane(v_lo, 2);
  float r0k = frdlane(r0_lo, 0);
  float r1k = frdlane(r1_lo, 0);

  for (int k = 0; k < 60; ++k)  FWD_STEP(RD_LO)    // k+3 <= 62: lo-only reads
  for (int k = 60; k < 99; ++k) FWD_STEP(RD_MIX)   // mixed, clamped
  {                                                // k = 99 peeled
    const int k = 99;
    float iuk = frcp(uk);
    Lrow[l * 101 + k] = u_lo * iuk;
    if (hiv) Lrow[ahi * 101 + k] = u_hi * iuk;
    float dk = P * iuk * iuk;
    sdh = (ahi == k) ? dk : sdh;                   // l==99 impossible
  }

  // ---- diagonal scale: w = y / d (register sd) ----
  float x0_lo = r0_lo * sdl, x1_lo = r1_lo * sdl;
  float x0_hi = r0_hi * sdh, x1_hi = r1_hi * sdh;

  // ---- backward: L~^T x = w, residual update with prefetched row reads ----
  float Ll = Lrow[99 * 101 + l];
  float Lh = hiv ? Lrow[99 * 101 + ahi] : 0.0f;
  for (int k = 99; k >= 1; --k) {
    float nLl = Lrow[(k - 1) * 101 + l];
    float nLh = hiv ? Lrow[(k - 1) * 101 + ahi] : 0.0f;
    float xk0 = frdpos(x0_lo, x0_hi, k);
    float xk1 = frdpos(x1_lo, x1_hi, k);
    if (l < k)   { x0_lo -= xk0 * Ll; x1_lo -= xk1 * Ll; }
    if (ahi < k) { x0_hi -= xk0 * Lh; x1_hi -= xk1 * Lh; }
    Ll = nLl; Lh = nLh;
  }

  // ---- h[p][j][d] = sinv * x[p] ----
  ws[OFF_H + l * 32 + j * 2 + 0] = sinvf * x0_lo;
  ws[OFF_H + l * 32 + j * 2 + 1] = sinvf * x1_lo;
  if (hiv) {
    ws[OFF_H + ahi * 32 + j * 2 + 0] = sinvf * x0_hi;
    ws[OFF_H + ahi * 32 + j * 2 + 1] = sinvf * x1_hi;
  }
}

// =============================== K_TAIL ====================================
// 16 blocks x 256 (4 waves -> barriers REQUIRED here).
#define L_H   0        // 3200
#define L_QT  3200     // 512
#define L_XL  3712     // 64
#define L_BC  3776     // 99*100 = 9900
#define L_Z   13676    // 99*32  = 3168
#define L_XT  16844    // 99*64  = 6336
#define L_PS  23180    // 4*64   = 256
#define L_TOT 23436

__global__ __launch_bounds__(256) void k_tail(
    const float* __restrict__ ls_in, const float* __restrict__ beta,
    const float* __restrict__ ws, float* __restrict__ out)
{
  extern __shared__ float lds[];
  const int tid = threadIdx.x;
  const float ls = ls_in[0];
  const float i2 = -0.5f / (ls * ls);

  for (int e = tid; e < 3200; e += 256) lds[L_H + e] = ws[OFF_H + e];
  for (int e = tid; e < 512; e += 256)  lds[L_QT + e] = ws[OFF_QT + e];
  if (tid < 64) lds[L_XL + tid] = ws[OFF_XL + tid];
  for (int e = tid; e < NT * NBINS; e += 256) {
    int t = e / NBINS, p = e - t * NBINS;
    float tst = 1.0f + (float)t * (1.0f / 99.0f);
    float dd = tst - ((float)p + 0.5f) * 0.01f;
    lds[L_BC + e] = expf(dd * dd * i2);
  }
  __syncthreads();

  // z[t][j][d] = sum_p Bc[t][p] * h[p][j][d]
  for (int dot = tid; dot < NT * 32; dot += 256) {
    int t = dot >> 5, jd = dot & 31;
    float acc = 0.f;
    for (int p = 0; p < NBINS; ++p)
      acc += lds[L_BC + t * NBINS + p] * lds[L_H + p * 32 + jd];
    lds[L_Z + dot] = acc;
  }
  __syncthreads();

  // xt[t][n][d] = xl[nd] + trel * sum_j qt[j][n] * z[t][j][d]
  for (int e = tid; e < NT * 64; e += 256) {
    int t = e >> 6, nd = e & 63, n = nd >> 1, d = nd & 1;
    float acc = 0.f;
    for (int jq = 0; jq < 16; ++jq)
      acc += lds[L_QT + jq * 32 + n] * lds[L_Z + t * 32 + jq * 2 + d];
    float trel = (float)t * (1.0f / 99.0f);
    lds[L_XT + e] = lds[L_XL + nd] + trel * acc;
  }
  __syncthreads();

  // intensity: 64 pairs per block, 4-way t-split
  {
    const int pl = tid & 63, tc = tid >> 6;
    const int gp = blockIdx.x * 64 + pl;
    const int i = gp >> 5, jj = gp & 31;
    const float bsum = beta[i] + beta[jj];
    const int t0 = tc * 25, t1 = (t0 + 25 < NT) ? t0 + 25 : NT;
    float acc = 0.f;
    for (int t = t0; t < t1; ++t) {
      float2 xi = *(const float2*)&lds[L_XT + t * 64 + 2 * i];
      float2 xj = *(const float2*)&lds[L_XT + t * 64 + 2 * jj];
      float dx = xi.x - xj.x, dy = xi.y - xj.y;
      float sq = fmaxf(dx * dx + dy * dy, 1e-12f);
      acc += expf(bsum - sqrtf(sq));
    }
    lds[L_PS + tc * 64 + pl] = acc;
  }
  __syncthreads();
  if (tid < 64) {
    float s = lds[L_PS + tid] + lds[L_PS + 64 + tid]
            + lds[L_PS + 128 + tid] + lds[L_PS + 192 + tid];
    out[blockIdx.x * 64 + tid] = s * (1.0f / 99.0f);
  }
}

extern "C" void kernel_launch(void* const* d_in, const int* in_sizes, int n_in,
                              void* d_out, int out_size, void* d_ws, size_t ws_size,
                              hipStream_t stream) {
  const float* x0    = (const float*)d_in[0];
  const float* v     = (const float*)d_in[1];
  const float* beta  = (const float*)d_in[2];
  const float* sigma = (const float*)d_in[3];
  // d_in[4] = x0c: unused (B_cross row 0 is zero)
  const float* ls    = (const float*)d_in[5];
  const float* Cq    = (const float*)d_in[6];
  float* out = (float*)d_out;
  float* ws  = (float*)d_ws;

  const size_t smem1 = (size_t)(100 * 101 + 64 * 101 + 512) * sizeof(float); // ~66.7 KB
  k1_all<<<16, 64, smem1, stream>>>(x0, v, sigma, ls, Cq, ws);
  k_tail<<<16, 256, (size_t)L_TOT * sizeof(float), stream>>>(ls, beta, ws, out);
}